// Round 1
// baseline (1348.573 us; speedup 1.0000x reference)
//
#include <hip/hip_runtime.h>
#include <math.h>

#define N_GT 256
#define M_PR 1024
#define LG   91

// ---------------------------------------------------------------------------
// Kernel 1: cost[i][j] = sqrt(|cgt_i - cpred_j|^2) + sum_l |lgt_i - lpred_j|
// One block per gt row i; 256 threads cover 1024 pred columns.
// ---------------------------------------------------------------------------
__global__ __launch_bounds__(256) void cost_kernel(
    const float* __restrict__ cgt, const float* __restrict__ cpred,
    const float* __restrict__ lgt, const float* __restrict__ lpred,
    float* __restrict__ cost)
{
    __shared__ float sg[LG];
    __shared__ float gx, gy;
    const int i   = blockIdx.x;
    const int tid = threadIdx.x;
    if (tid < LG) sg[tid] = lgt[i * LG + tid];
    if (tid == 0) { gx = cgt[2 * i]; gy = cgt[2 * i + 1]; }
    __syncthreads();
    for (int j = tid; j < M_PR; j += 256) {
        float dx = gx - cpred[2 * j];
        float dy = gy - cpred[2 * j + 1];
        float cd = sqrtf(dx * dx + dy * dy);
        const float* lp = lpred + j * LG;
        float s = 0.f;
        #pragma unroll 7
        for (int l = 0; l < LG; ++l) s += fabsf(sg[l] - lp[l]);
        cost[i * M_PR + j] = cd + s;
    }
}

// ---------------------------------------------------------------------------
// Kernel 2: Jonker-Volgenant shortest-augmenting-path LSA, exact replica of
// the numpy reference (f64 duals, first-occurrence argmin tie-break).
// Single block, 256 threads (4 waves). All state in LDS.
// Output layout (float32): [0..255]=row, [256..511]=col, [512]=cost.
// ---------------------------------------------------------------------------
__global__ __launch_bounds__(256) void lsa_kernel(
    const float* __restrict__ cost,
    const float* __restrict__ cgt, const float* __restrict__ cpred,
    float* __restrict__ out)
{
    const int n = N_GT, m = M_PR;
    const double INF = 1e18;

    __shared__ double v[M_PR + 1], minv[M_PR + 1];
    __shared__ double u[N_GT + 1];
    __shared__ int    p[M_PR + 1], way[M_PR + 1], used[M_PR + 1];
    __shared__ int    sj0, si0;
    __shared__ double sdelta;
    __shared__ double rv[4];
    __shared__ int    rj[4];
    __shared__ int    colarr[N_GT];

    const int tid  = threadIdx.x;
    const int lane = tid & 63;
    const int wid  = tid >> 6;

    for (int j = tid; j <= m; j += 256) { v[j] = 0.0; p[j] = 0; }
    for (int k = tid; k <= n; k += 256) u[k] = 0.0;
    __syncthreads();

    for (int i = 1; i <= n; ++i) {
        if (tid == 0) { p[0] = i; sj0 = 0; }
        for (int j = tid; j <= m; j += 256) { minv[j] = INF; used[j] = 0; }
        __syncthreads();

        while (true) {
            if (tid == 0) { used[sj0] = 1; si0 = p[sj0]; }
            __syncthreads();
            const int j0 = sj0;
            const int i0 = si0;
            const float* crow = cost + (size_t)(i0 - 1) * m;
            const double ui = u[i0];

            // scan free columns: relax minv, track local argmin (ties -> smallest j)
            double bestv = INF; int bestj = m;
            for (int j = tid + 1; j <= m; j += 256) {
                if (!used[j]) {
                    double cur = (double)crow[j - 1] - ui - v[j];
                    if (cur < minv[j]) { minv[j] = cur; way[j] = j0; }
                    double mv = minv[j];
                    if (mv < bestv || (mv == bestv && j < bestj)) { bestv = mv; bestj = j; }
                }
            }
            // wave (64-lane) shuffle reduction with tie-break
            for (int off = 32; off > 0; off >>= 1) {
                double ov = __shfl_down(bestv, off, 64);
                int    oj = __shfl_down(bestj, off, 64);
                if (ov < bestv || (ov == bestv && oj < bestj)) { bestv = ov; bestj = oj; }
            }
            if (lane == 0) { rv[wid] = bestv; rj[wid] = bestj; }
            __syncthreads();
            if (tid == 0) {
                double bv = rv[0]; int bj = rj[0];
                for (int w = 1; w < 4; ++w)
                    if (rv[w] < bv || (rv[w] == bv && rj[w] < bj)) { bv = rv[w]; bj = rj[w]; }
                sdelta = bv; sj0 = bj;
            }
            __syncthreads();
            const double delta = sdelta;
            const int    j1    = sj0;
            for (int j = tid; j <= m; j += 256) {
                if (used[j]) { u[p[j]] += delta; v[j] -= delta; }
                else         { minv[j] -= delta; }
            }
            __syncthreads();
            if (p[j1] == 0) break;   // uniform: all threads read same p[j1]
        }

        // augment alternating path (sequential, tiny)
        if (tid == 0) {
            int j0 = sj0;
            while (j0 != 0) { int j1 = way[j0]; p[j0] = p[j1]; j0 = j1; }
        }
        __syncthreads();
    }

    // gather column assignment
    for (int j = tid + 1; j <= m; j += 256)
        if (p[j] > 0) colarr[p[j] - 1] = j - 1;
    __syncthreads();

    out[tid]        = (float)tid;            // row = arange(n)
    out[N_GT + tid] = (float)colarr[tid];    // col
    if (tid == 0) {
        float s = 0.f;
        for (int i = 0; i < n; ++i) {
            int c = colarr[i];
            float dx = cgt[2 * i]     - cpred[2 * c];
            float dy = cgt[2 * i + 1] - cpred[2 * c + 1];
            s += sqrtf(dx * dx + dy * dy);
        }
        out[2 * N_GT] = s;                   // cost = sum of matched distances
    }
}

extern "C" void kernel_launch(void* const* d_in, const int* in_sizes, int n_in,
                              void* d_out, int out_size, void* d_ws, size_t ws_size,
                              hipStream_t stream)
{
    const float* cgt   = (const float*)d_in[0];   // (256, 2)
    const float* cpred = (const float*)d_in[1];   // (1024, 2)
    const float* lgt   = (const float*)d_in[2];   // (256, 91)
    const float* lpred = (const float*)d_in[3];   // (1024, 91)
    float* out  = (float*)d_out;                  // 513 floats
    float* cost = (float*)d_ws;                   // 256*1024 floats = 1 MB

    cost_kernel<<<N_GT, 256, 0, stream>>>(cgt, cpred, lgt, lpred, cost);
    lsa_kernel<<<1, 256, 0, stream>>>(cost, cgt, cpred, out);
}

// Round 3
// 916.683 us; speedup vs baseline: 1.4711x; 1.4711x over previous
//
#include <hip/hip_runtime.h>
#include <math.h>

#define N_GT 256
#define M_PR 1024
#define LG   91
#define CPL  16   // columns per lane (64 lanes * 16 = 1024)

// ---------------------------------------------------------------------------
// Kernel 1: cost[i][j] = sqrt(|cgt_i - cpred_j|^2) + sum_l |lgt_i - lpred_j|
// One block per gt row i; 256 threads cover 1024 pred columns.
// ---------------------------------------------------------------------------
__global__ __launch_bounds__(256) void cost_kernel(
    const float* __restrict__ cgt, const float* __restrict__ cpred,
    const float* __restrict__ lgt, const float* __restrict__ lpred,
    float* __restrict__ cost)
{
    __shared__ float sg[LG];
    __shared__ float gx, gy;
    const int i   = blockIdx.x;
    const int tid = threadIdx.x;
    if (tid < LG) sg[tid] = lgt[i * LG + tid];
    if (tid == 0) { gx = cgt[2 * i]; gy = cgt[2 * i + 1]; }
    __syncthreads();
    for (int j = tid; j < M_PR; j += 256) {
        float dx = gx - cpred[2 * j];
        float dy = gy - cpred[2 * j + 1];
        float cd = sqrtf(dx * dx + dy * dy);
        const float* lp = lpred + j * LG;
        float s = 0.f;
        #pragma unroll 7
        for (int l = 0; l < LG; ++l) s += fabsf(sg[l] - lp[l]);
        cost[i * M_PR + j] = cd + s;
    }
}

// ---------------------------------------------------------------------------
// Kernel 2: Jonker-Volgenant LSA, single wave (64 lanes), zero barriers in
// the Dijkstra inner loop. Per-lane registers hold per-column state (16
// cols/lane, statically unrolled). Absolute-distance form: A[j] holds
// reduced-cost-to-j shifted by the cumulative delta D at relax time, so
// D_new = min_unused A and the per-step "minv -= delta" sweep vanishes.
// Dual updates (u/v) deferred to row end via markD (cum-delta at settle
// time); verified equivalent to the reference's per-step updates because
// each path row's u is read exactly once, before any update touching it.
// LDS only for p (matching), u (row duals), way (path parents), colarr.
// Output layout (float32): [0..255]=row, [256..511]=col, [512]=cost.
// ---------------------------------------------------------------------------
__global__ __launch_bounds__(64) void lsa_kernel(
    const float* __restrict__ cost,
    const float* __restrict__ cgt, const float* __restrict__ cpred,
    float* __restrict__ out)
{
    __shared__ double u[N_GT + 1];
    __shared__ int    p[M_PR + 1];
    __shared__ int    way[M_PR + 1];
    __shared__ int    colarr[N_GT];

    const int lane = threadIdx.x;

    double v[CPL], A[CPL], markD[CPL];
    int    bw[CPL];

    for (int r = lane; r <= N_GT; r += 64) u[r] = 0.0;
    for (int j = lane; j <= M_PR; j += 64) p[j] = 0;
    for (int r = lane; r < N_GT; r += 64) colarr[r] = 0;
    #pragma unroll
    for (int k = 0; k < CPL; ++k) { v[k] = 0.0; bw[k] = 0; markD[k] = 0.0; }
    __syncthreads();

    for (int i = 1; i <= N_GT; ++i) {
        #pragma unroll
        for (int k = 0; k < CPL; ++k) A[k] = 1e18;
        unsigned usedmask = 0u;
        double D  = 0.0;     // cumulative delta (settled distance)
        int    j0 = 0;
        int    i0 = i;       // virtual p[0] = i
        while (true) {
            const float* crow = cost + (size_t)(i0 - 1) * M_PR;
            double ui   = u[i0];        // LDS broadcast read (row-start value)
            double base = ui - D;       // cur_abs = c - base - v[k]

            double   bestA  = 1e18;
            unsigned bestjw = 0xFFFFFFFFu;
            #pragma unroll
            for (int k = 0; k < CPL; ++k) {
                const int col = lane + 1 + 64 * k;      // 1-based column
                double c = (double)crow[col - 1];
                bool isj0 = (col == j0);                // mark just-settled col
                if (isj0) { usedmask |= (1u << k); markD[k] = D; }
                bool unused = ((usedmask >> k) & 1u) == 0u;
                double cur = c - base - v[k];
                bool upd = unused && (cur < A[k]);
                A[k]  = upd ? cur : A[k];
                bw[k] = upd ? j0  : bw[k];
                if (unused && A[k] < bestA) {           // strict < keeps smallest col
                    bestA  = A[k];
                    bestjw = ((unsigned)col << 11) | (unsigned)bw[k];
                }
            }
            // 64-lane butterfly argmin; ties -> smallest col (col in high bits)
            #pragma unroll
            for (int off = 1; off < 64; off <<= 1) {
                double   oA  = __shfl_xor(bestA, off, 64);
                unsigned ojw = (unsigned)__shfl_xor((int)bestjw, off, 64);
                bool b = (oA < bestA) || (oA == bestA && ojw < bestjw);
                bestA  = b ? oA  : bestA;
                bestjw = b ? ojw : bestjw;
            }
            D = bestA;
            int j1 = (int)(bestjw >> 11);
            int w1 = (int)(bestjw & 0x7FFu);
            if (lane == 0) way[j1] = w1;   // parent fixed at settle time
            int pj = p[j1];                // LDS broadcast read
            j0 = j1;
            if (pj == 0) break;            // free column found
            i0 = pj;
        }
        // ---- deferred dual flush (uses pre-augmentation p) ----
        if (lane == 0) u[i] += D;          // virtual col 0: markD = 0
        #pragma unroll
        for (int k = 0; k < CPL; ++k) {
            if ((usedmask >> k) & 1u) {
                const int col = lane + 1 + 64 * k;
                double adj = D - markD[k];
                v[k] -= adj;
                int r = p[col];            // distinct rows across used cols
                u[r] += adj;               // distinct LDS addresses, no race
            }
        }
        __syncthreads();
        // ---- augment alternating path (virtual p[0] == i) ----
        if (lane == 0) {
            int jj = j0;
            while (jj != 0) {
                int jp = way[jj];
                p[jj] = (jp == 0) ? i : p[jp];   // FIX: substitute row i at chain end
                jj = jp;
            }
        }
        __syncthreads();
    }

    // gather column assignment
    #pragma unroll
    for (int k = 0; k < CPL; ++k) {
        int j  = lane + 1 + 64 * k;
        int pr = p[j];
        if (pr > 0) colarr[pr - 1] = j - 1;
    }
    __syncthreads();

    for (int idx = lane; idx < N_GT; idx += 64) {
        out[idx]        = (float)idx;           // row = arange(n)
        out[N_GT + idx] = (float)colarr[idx];   // col
    }
    // cost = sum of matched Euclidean distances (parallel + butterfly sum)
    float s = 0.f;
    for (int idx = lane; idx < N_GT; idx += 64) {
        int c = colarr[idx];
        c = (c < 0) ? 0 : (c >= M_PR ? M_PR - 1 : c);   // defensive clamp
        float dx = cgt[2 * idx]     - cpred[2 * c];
        float dy = cgt[2 * idx + 1] - cpred[2 * c + 1];
        s += sqrtf(dx * dx + dy * dy);
    }
    #pragma unroll
    for (int off = 1; off < 64; off <<= 1) s += __shfl_xor(s, off, 64);
    if (lane == 0) out[2 * N_GT] = s;
}

extern "C" void kernel_launch(void* const* d_in, const int* in_sizes, int n_in,
                              void* d_out, int out_size, void* d_ws, size_t ws_size,
                              hipStream_t stream)
{
    const float* cgt   = (const float*)d_in[0];   // (256, 2)
    const float* cpred = (const float*)d_in[1];   // (1024, 2)
    const float* lgt   = (const float*)d_in[2];   // (256, 91)
    const float* lpred = (const float*)d_in[3];   // (1024, 91)
    float* out  = (float*)d_out;                  // 513 floats
    float* cost = (float*)d_ws;                   // 256*1024 floats = 1 MB

    cost_kernel<<<N_GT, 256, 0, stream>>>(cgt, cpred, lgt, lpred, cost);
    lsa_kernel<<<1, 64, 0, stream>>>(cost, cgt, cpred, out);
}

// Round 4
// 496.097 us; speedup vs baseline: 2.7184x; 1.8478x over previous
//
#include <hip/hip_runtime.h>
#include <math.h>

#define N_GT 256
#define M_PR 1024
#define LG   91
#define CPL  16   // columns per lane (64 lanes * 16 = 1024)

// ---------------------------------------------------------------------------
// Kernel 1: cost[i][j] = sqrt(|cgt_i - cpred_j|^2) + sum_l |lgt_i - lpred_j|
// One block per gt row i; 256 threads cover 1024 pred columns.
// Fused: also computes rowmin[i] / rowarg[i] (argmin col, smallest-col ties)
// for the JV greedy initialization -- values are already in registers.
// ---------------------------------------------------------------------------
__global__ __launch_bounds__(256) void cost_kernel(
    const float* __restrict__ cgt, const float* __restrict__ cpred,
    const float* __restrict__ lgt, const float* __restrict__ lpred,
    float* __restrict__ cost, float* __restrict__ rowmin, int* __restrict__ rowarg)
{
    __shared__ float sg[LG];
    __shared__ float gx, gy;
    __shared__ float wmin[4];
    __shared__ int   warg[4];
    const int i   = blockIdx.x;
    const int tid = threadIdx.x;
    if (tid < LG) sg[tid] = lgt[i * LG + tid];
    if (tid == 0) { gx = cgt[2 * i]; gy = cgt[2 * i + 1]; }
    __syncthreads();
    float bv = 1e30f; int bj = 0;
    for (int j = tid; j < M_PR; j += 256) {
        float dx = gx - cpred[2 * j];
        float dy = gy - cpred[2 * j + 1];
        float cd = sqrtf(dx * dx + dy * dy);
        const float* lp = lpred + j * LG;
        float s = 0.f;
        #pragma unroll 7
        for (int l = 0; l < LG; ++l) s += fabsf(sg[l] - lp[l]);
        float cv = cd + s;
        cost[i * M_PR + j] = cv;
        if (cv < bv) { bv = cv; bj = j; }   // per-thread cols ascending -> first occurrence
    }
    const int lane = tid & 63, wid = tid >> 6;
    #pragma unroll
    for (int off = 1; off < 64; off <<= 1) {
        float ov = __shfl_xor(bv, off, 64);
        int   oj = __shfl_xor(bj, off, 64);
        if (ov < bv || (ov == bv && oj < bj)) { bv = ov; bj = oj; }
    }
    if (lane == 0) { wmin[wid] = bv; warg[wid] = bj; }
    __syncthreads();
    if (tid == 0) {
        for (int w = 1; w < 4; ++w)
            if (wmin[w] < bv || (wmin[w] == bv && warg[w] < bj)) { bv = wmin[w]; bj = warg[w]; }
        rowmin[i] = bv; rowarg[i] = bj;
    }
}

// ---------------------------------------------------------------------------
// Kernel 2: Jonker-Volgenant LSA with greedy row-reduction init, single wave
// (64 lanes), zero barriers in the Dijkstra inner loop.
// Init: u[i] = rowmin[i], v = 0 (feasible, tight), p[argmin col] = smallest
// claiming row (deterministic LDS atomicMin). Only unmatched rows run the
// shortest-augmenting-path search. Unique optimum => identical output to ref.
// Per-lane registers hold per-column state (16 cols/lane). Absolute-distance
// form: A[j] = reduced-cost + cum-delta at relax time, so D_new = min A and
// the per-step "minv -= delta" sweep vanishes. Dual updates deferred to row
// end via markD. Output (f32): [0..255]=row, [256..511]=col, [512]=cost.
// ---------------------------------------------------------------------------
__global__ __launch_bounds__(64) void lsa_kernel(
    const float* __restrict__ cost,
    const float* __restrict__ rowmin, const int* __restrict__ rowarg,
    const float* __restrict__ cgt, const float* __restrict__ cpred,
    float* __restrict__ out)
{
    __shared__ double u[N_GT + 1];
    __shared__ int    p[M_PR + 1];
    __shared__ int    pmin[M_PR + 1];
    __shared__ int    way[M_PR + 1];
    __shared__ int    colarr[N_GT];
    __shared__ int    unm[N_GT];

    const int lane = threadIdx.x;

    double v[CPL], A[CPL], markD[CPL];
    int    bw[CPL];

    for (int j = lane; j <= M_PR; j += 64) { p[j] = 0; pmin[j] = 0x7FFFFFFF; }
    for (int r = lane; r < N_GT; r += 64) colarr[r] = 0;
    if (lane == 0) u[0] = 0.0;
    #pragma unroll
    for (int k = 0; k < CPL; ++k) { v[k] = 0.0; bw[k] = 0; markD[k] = 0.0; }
    __syncthreads();

    // ---- greedy init: claim argmin cols, smallest row wins (deterministic) ----
    #pragma unroll
    for (int g = 0; g < 4; ++g) {
        int i = g * 64 + lane;                 // 0-based row
        u[i + 1] = (double)rowmin[i];
        atomicMin(&pmin[rowarg[i] + 1], i + 1);
    }
    __syncthreads();
    for (int j = lane + 1; j <= M_PR; j += 64)
        p[j] = (pmin[j] == 0x7FFFFFFF) ? 0 : pmin[j];
    // unmatched list, order-preserving ballot compaction
    int base = 0;
    #pragma unroll
    for (int g = 0; g < 4; ++g) {
        int i = g * 64 + lane;
        bool um = (pmin[rowarg[i] + 1] != i + 1);
        unsigned long long mask = __ballot(um);
        int pos = base + __popcll(mask & ((1ull << lane) - 1ull));
        if (um) unm[pos] = i + 1;              // 1-based row
        base += __popcll(mask);
    }
    const int nunm = base;
    __syncthreads();

    for (int t = 0; t < nunm; ++t) {
        const int i = unm[t];                  // 1-based unmatched row
        #pragma unroll
        for (int k = 0; k < CPL; ++k) A[k] = 1e18;
        unsigned usedmask = 0u;
        double D  = 0.0;     // cumulative delta (settled distance)
        int    j0 = 0;
        int    i0 = i;       // virtual p[0] = i
        while (true) {
            const float* crow = cost + (size_t)(i0 - 1) * M_PR;
            double ui   = u[i0];        // LDS broadcast read (search-start value)
            double base2 = ui - D;      // cur_abs = c - base2 - v[k]

            double   bestA  = 1e18;
            unsigned bestjw = 0xFFFFFFFFu;
            #pragma unroll
            for (int k = 0; k < CPL; ++k) {
                const int col = lane + 1 + 64 * k;      // 1-based column
                double c = (double)crow[col - 1];
                bool isj0 = (col == j0);                // mark just-settled col
                if (isj0) { usedmask |= (1u << k); markD[k] = D; }
                bool unused = ((usedmask >> k) & 1u) == 0u;
                double cur = c - base2 - v[k];
                bool upd = unused && (cur < A[k]);
                A[k]  = upd ? cur : A[k];
                bw[k] = upd ? j0  : bw[k];
                if (unused && A[k] < bestA) {           // strict < keeps smallest col
                    bestA  = A[k];
                    bestjw = ((unsigned)col << 11) | (unsigned)bw[k];
                }
            }
            // 64-lane butterfly argmin; ties -> smallest col (col in high bits)
            #pragma unroll
            for (int off = 1; off < 64; off <<= 1) {
                double   oA  = __shfl_xor(bestA, off, 64);
                unsigned ojw = (unsigned)__shfl_xor((int)bestjw, off, 64);
                bool b = (oA < bestA) || (oA == bestA && ojw < bestjw);
                bestA  = b ? oA  : bestA;
                bestjw = b ? ojw : bestjw;
            }
            D = bestA;
            int j1 = (int)(bestjw >> 11);
            int w1 = (int)(bestjw & 0x7FFu);
            if (lane == 0) way[j1] = w1;   // parent fixed at settle time
            int pj = p[j1];                // LDS broadcast read
            j0 = j1;
            if (pj == 0) break;            // free column found
            i0 = pj;
        }
        // ---- deferred dual flush (uses pre-augmentation p) ----
        if (lane == 0) u[i] += D;          // virtual col 0: markD = 0
        #pragma unroll
        for (int k = 0; k < CPL; ++k) {
            if ((usedmask >> k) & 1u) {
                const int col = lane + 1 + 64 * k;
                double adj = D - markD[k];
                v[k] -= adj;
                int r = p[col];            // distinct rows across used cols
                u[r] += adj;               // distinct LDS addresses, no race
            }
        }
        __syncthreads();
        // ---- augment alternating path (virtual p[0] == i) ----
        if (lane == 0) {
            int jj = j0;
            while (jj != 0) {
                int jp = way[jj];
                p[jj] = (jp == 0) ? i : p[jp];
                jj = jp;
            }
        }
        __syncthreads();
    }

    // gather column assignment
    #pragma unroll
    for (int k = 0; k < CPL; ++k) {
        int j  = lane + 1 + 64 * k;
        int pr = p[j];
        if (pr > 0) colarr[pr - 1] = j - 1;
    }
    __syncthreads();

    for (int idx = lane; idx < N_GT; idx += 64) {
        out[idx]        = (float)idx;           // row = arange(n)
        out[N_GT + idx] = (float)colarr[idx];   // col
    }
    // cost = sum of matched Euclidean distances (parallel + butterfly sum)
    float s = 0.f;
    for (int idx = lane; idx < N_GT; idx += 64) {
        int c = colarr[idx];
        c = (c < 0) ? 0 : (c >= M_PR ? M_PR - 1 : c);   // defensive clamp
        float dx = cgt[2 * idx]     - cpred[2 * c];
        float dy = cgt[2 * idx + 1] - cpred[2 * c + 1];
        s += sqrtf(dx * dx + dy * dy);
    }
    #pragma unroll
    for (int off = 1; off < 64; off <<= 1) s += __shfl_xor(s, off, 64);
    if (lane == 0) out[2 * N_GT] = s;
}

extern "C" void kernel_launch(void* const* d_in, const int* in_sizes, int n_in,
                              void* d_out, int out_size, void* d_ws, size_t ws_size,
                              hipStream_t stream)
{
    const float* cgt   = (const float*)d_in[0];   // (256, 2)
    const float* cpred = (const float*)d_in[1];   // (1024, 2)
    const float* lgt   = (const float*)d_in[2];   // (256, 91)
    const float* lpred = (const float*)d_in[3];   // (1024, 91)
    float* out  = (float*)d_out;                  // 513 floats

    char* ws = (char*)d_ws;
    float* cost   = (float*)ws;                        // 1 MB
    float* rowmin = (float*)(ws + (size_t)N_GT * M_PR * 4);          // 1 KB
    int*   rowarg = (int*)  (ws + (size_t)N_GT * M_PR * 4 + N_GT*4); // 1 KB

    cost_kernel<<<N_GT, 256, 0, stream>>>(cgt, cpred, lgt, lpred, cost, rowmin, rowarg);
    lsa_kernel<<<1, 64, 0, stream>>>(cost, rowmin, rowarg, cgt, cpred, out);
}